// Round 1
// baseline (1743.727 us; speedup 1.0000x reference)
//
#include <hip/hip_runtime.h>
#include <math.h>

#define N 16384
#define KNN 16

__device__ __forceinline__ float lrelu(float a) { return a > 0.f ? a : 0.01f * a; }

// ---------------------------------------------------------------------------
// prep: pts4 = (x,y,z,x^2+y^2+z^2), cf = pconv2(lrelu(pconv1(pts))), imfT
// ---------------------------------------------------------------------------
__global__ __launch_bounds__(128) void prep_kernel(
    const float* __restrict__ img, const float* __restrict__ cloud,
    const float* __restrict__ p1w, const float* __restrict__ p1b,
    const float* __restrict__ p2w, const float* __restrict__ p2b,
    float4* __restrict__ pts4, float* __restrict__ cf, float* __restrict__ imfT) {
  int i = blockIdx.x, t = threadIdx.x;
  __shared__ float h[64];
  __shared__ float p[3];
  if (t < 3) p[t] = cloud[i * 3 + t];
  __syncthreads();
  float x = p[0], y = p[1], z = p[2];
  if (t == 0) {
    float sq = x * x + y * y + z * z;
    pts4[i] = make_float4(x, y, z, sq);
  }
  if (t < 64) {
    float a = p1b[t] + x * p1w[t * 3] + y * p1w[t * 3 + 1] + z * p1w[t * 3 + 2];
    h[t] = lrelu(a);
  }
  if (t < 32) imfT[i * 32 + t] = img[t * N + i];
  __syncthreads();
  // cf channel t (128 threads, 128 channels), no activation after pconv2
  float acc = p2b[t];
  const float* wr = p2w + t * 64;
  for (int k = 0; k < 64; ++k) acc += h[k] * wr[k];
  cf[i * 128 + t] = acc;
}

// ---------------------------------------------------------------------------
// pad final_w [32,416] -> [32,448] zero-padded
// ---------------------------------------------------------------------------
__global__ void padw_kernel(const float* __restrict__ fw, float* __restrict__ fwp) {
  int t = blockIdx.x * 256 + threadIdx.x;
  if (t < 32 * 448) {
    int c = t / 448, j = t % 448;
    fwp[t] = (j < 416) ? fw[c * 416 + j] : 0.f;
  }
}

// ---------------------------------------------------------------------------
// KNN: one wave per query. Wave-held top-16 (lanes 0-15 each hold one u64
// key = (d2_bits<<32)|index). Threshold = max of held keys; ballot-test per
// 64-candidate step; rare serial inserts. Then dist/softmax weights.
// ---------------------------------------------------------------------------
#define TILE 2048
__global__ __launch_bounds__(256) void knn_kernel(
    const float4* __restrict__ pts4, int* __restrict__ nidx, float* __restrict__ nwgt) {
  __shared__ alignas(16) float4 tile[TILE];
  int t = threadIdx.x;
  int wv = t >> 6, lane = t & 63;
  int wid = blockIdx.x * 4 + wv;  // query index
  float4 q = pts4[wid];
  unsigned long long mykey = ~0ULL;   // sentinel: larger than any real key
  unsigned long long curmax = ~0ULL;  // max of the 16 held keys

  for (int base = 0; base < N; base += TILE) {
    __syncthreads();
    for (int e = t; e < TILE; e += 256) tile[e] = pts4[base + e];
    __syncthreads();
    for (int s = 0; s < TILE; s += 64) {
      int j = base + s + lane;
      float4 c = tile[s + lane];
      float d2 = q.w + c.w - 2.f * (q.x * c.x + q.y * c.y + q.z * c.z);
      d2 = fmaxf(d2, 0.f);
      unsigned long long key =
          ((unsigned long long)__float_as_uint(d2) << 32) | (unsigned)j;
      unsigned long long mask = __ballot(key < curmax);
      while (mask) {
        int src = __builtin_ctzll(mask);
        mask &= mask - 1;
        unsigned long long kk = __shfl(key, src);
        if (kk < curmax) {
          // replace current max holder (unique: keys carry unique indices)
          unsigned long long hm = __ballot(lane < KNN && mykey == curmax);
          int holder = __builtin_ctzll(hm);
          if (lane == holder) mykey = kk;
          // recompute max over lanes 0-15
          unsigned long long m = (lane < KNN) ? mykey : 0ULL;
          #pragma unroll
          for (int off = 1; off < 64; off <<= 1) {
            unsigned long long o = __shfl_xor(m, off);
            m = (o > m) ? o : m;
          }
          curmax = m;
        }
      }
    }
  }
  // epilogue: distances + softmax weights (lanes 0-15 hold the set)
  int id = (lane < KNN) ? (int)(unsigned)(mykey & 0xffffffffULL) : 0;
  float4 c = pts4[id];
  float dx = q.x - c.x, dy = q.y - c.y, dz = q.z - c.z;
  float dd = dx * dx + dy * dy + dz * dz;
  float dist = sqrtf(fmaxf(dd, 1e-12f));
  float md = (lane < KNN) ? dist : INFINITY;  // min dist over the 16
  #pragma unroll
  for (int off = 1; off < KNN; off <<= 1) md = fminf(md, __shfl_xor(md, off));
  float e = expf(md - dist);  // exp(-dist - max(-dist))
  float se = (lane < KNN) ? e : 0.f;
  #pragma unroll
  for (int off = 1; off < KNN; off <<= 1) se += __shfl_xor(se, off);
  if (lane < KNN) {
    nidx[wid * KNN + lane] = id;
    nwgt[wid * KNN + lane] = e / se;
  }
}

// ---------------------------------------------------------------------------
// sf path: per point, gather nb_img[16,32], conv1->lrelu->conv2, weighted max
// ---------------------------------------------------------------------------
__global__ __launch_bounds__(256) void sf_kernel(
    const float* __restrict__ imfT, const int* __restrict__ nidx,
    const float* __restrict__ nwgt, const float* __restrict__ c1w,
    const float* __restrict__ c1b, const float* __restrict__ c2w,
    const float* __restrict__ c2b, float* __restrict__ sfmax) {
  int i = blockIdx.x, t = threadIdx.x;
  __shared__ alignas(16) float nb[16 * 32];
  __shared__ alignas(16) float h1[16 * 64];
  __shared__ int ids[16];
  __shared__ float wg[16];
  if (t < 16) { ids[t] = nidx[i * 16 + t]; wg[t] = nwgt[i * 16 + t]; }
  __syncthreads();
  for (int e = t; e < 512; e += 256) {
    int k = e >> 5, c = e & 31;
    nb[e] = imfT[ids[k] * 32 + c];
  }
  __syncthreads();
  for (int o = t; o < 1024; o += 256) {  // 16 nbr x 64 ch
    int k = o >> 6, c = o & 63;
    float acc = c1b[c];
    const float* wr = c1w + c * 32;
    const float* in = nb + k * 32;
    #pragma unroll
    for (int d = 0; d < 32; d += 4) {
      float4 w4 = *(const float4*)(wr + d);
      float4 i4 = *(const float4*)(in + d);
      acc += w4.x * i4.x + w4.y * i4.y + w4.z * i4.z + w4.w * i4.w;
    }
    h1[o] = lrelu(acc);
  }
  __syncthreads();
  int ch = t >> 1, kh = (t & 1) * 8;
  float m = -INFINITY;
  const float* wr = c2w + ch * 64;
  for (int k = kh; k < kh + 8; ++k) {
    float acc = c2b[ch];
    const float* in = h1 + k * 64;
    #pragma unroll
    for (int d = 0; d < 64; d += 4) {
      float4 w4 = *(const float4*)(wr + d);
      float4 i4 = *(const float4*)(in + d);
      acc += w4.x * i4.x + w4.y * i4.y + w4.z * i4.z + w4.w * i4.w;
    }
    m = fmaxf(m, acc * wg[k]);  // no activation after conv2
  }
  m = fmaxf(m, __shfl_xor(m, 1));
  if ((t & 1) == 0) sfmax[i * 128 + ch] = m;
}

// ---------------------------------------------------------------------------
// sfp path: per point, gather nb_cf[16,128], psconv1->lrelu->psconv2, wmax
// ---------------------------------------------------------------------------
__global__ __launch_bounds__(256) void sfp_kernel(
    const float* __restrict__ cf, const int* __restrict__ nidx,
    const float* __restrict__ nwgt, const float* __restrict__ w1,
    const float* __restrict__ b1, const float* __restrict__ w2,
    const float* __restrict__ b2, float* __restrict__ sfpmax) {
  int i = blockIdx.x, t = threadIdx.x;
  __shared__ alignas(16) float nb[16 * 128];   // 8 KB
  __shared__ alignas(16) float s1[16 * 256];   // 16 KB
  __shared__ int ids[16];
  __shared__ float wg[16];
  if (t < 16) { ids[t] = nidx[i * 16 + t]; wg[t] = nwgt[i * 16 + t]; }
  __syncthreads();
  for (int e = t; e < 2048; e += 256) {
    int k = e >> 7, c = e & 127;
    nb[e] = cf[ids[k] * 128 + c];
  }
  __syncthreads();
  {  // s1: thread t owns channel t for all 16 neighbors
    float acc[16];
    float bb = b1[t];
    #pragma unroll
    for (int k = 0; k < 16; ++k) acc[k] = bb;
    const float* wr = w1 + t * 128;
    for (int d = 0; d < 128; d += 4) {
      float4 w4 = *(const float4*)(wr + d);
      #pragma unroll
      for (int k = 0; k < 16; ++k) {
        float4 i4 = *(const float4*)(nb + k * 128 + d);
        acc[k] += w4.x * i4.x + w4.y * i4.y + w4.z * i4.z + w4.w * i4.w;
      }
    }
    #pragma unroll
    for (int k = 0; k < 16; ++k) s1[k * 256 + t] = lrelu(acc[k]);
  }
  __syncthreads();
  {  // psconv2 + weighted max: ch = t>>1, 8 neighbors per thread
    int ch = t >> 1, kh = (t & 1) * 8;
    float acc[8];
    float bb = b2[ch];
    #pragma unroll
    for (int k = 0; k < 8; ++k) acc[k] = bb;
    const float* wr = w2 + ch * 256;
    for (int d = 0; d < 256; d += 4) {
      float4 w4 = *(const float4*)(wr + d);
      #pragma unroll
      for (int k = 0; k < 8; ++k) {
        float4 i4 = *(const float4*)(s1 + (kh + k) * 256 + d);
        acc[k] += w4.x * i4.x + w4.y * i4.y + w4.z * i4.z + w4.w * i4.w;
      }
    }
    float m = -INFINITY;
    #pragma unroll
    for (int k = 0; k < 8; ++k) m = fmaxf(m, acc[k] * wg[kh + k]);
    m = fmaxf(m, __shfl_xor(m, 1));
    if ((t & 1) == 0) sfpmax[i * 128 + ch] = m;
  }
}

// ---------------------------------------------------------------------------
// final: out[c][i] = fb[c] + sum_j lrelu(concat[sfp,imf,sf,cf][i][j]) * fw[c][j]
// 64 points per block, LDS-tiled over j (448 padded cols)
// ---------------------------------------------------------------------------
__global__ __launch_bounds__(256) void final_kernel(
    const float* __restrict__ sfpmax, const float* __restrict__ imfT,
    const float* __restrict__ sfmax, const float* __restrict__ cf,
    const float* __restrict__ fwp, const float* __restrict__ fb,
    float* __restrict__ out) {
  __shared__ float feat[64][65];
  int t = threadIdx.x;
  int pbase = blockIdx.x * 64;
  int p = t & 63, cg = t >> 6;
  float acc[8];
  #pragma unroll
  for (int c = 0; c < 8; ++c) acc[c] = fb[cg * 8 + c];
  for (int jt = 0; jt < 448; jt += 64) {
    __syncthreads();
    for (int e = t; e < 64 * 64; e += 256) {
      int pp = e >> 6, jj = e & 63;
      int j = jt + jj;
      int pt = pbase + pp;
      float v;
      if (j < 128)      v = sfpmax[pt * 128 + j];
      else if (j < 160) v = imfT[pt * 32 + j - 128];
      else if (j < 288) v = sfmax[pt * 128 + j - 160];
      else if (j < 416) v = cf[pt * 128 + j - 288];
      else              v = 0.f;
      feat[pp][jj] = lrelu(v);
    }
    __syncthreads();
    for (int jj = 0; jj < 64; ++jj) {
      float f = feat[p][jj];
      #pragma unroll
      for (int c = 0; c < 8; ++c)
        acc[c] += f * fwp[(cg * 8 + c) * 448 + jt + jj];
    }
  }
  #pragma unroll
  for (int c = 0; c < 8; ++c) out[(cg * 8 + c) * N + pbase + p] = acc[c];
}

// ---------------------------------------------------------------------------
extern "C" void kernel_launch(void* const* d_in, const int* in_sizes, int n_in,
                              void* d_out, int out_size, void* d_ws, size_t ws_size,
                              hipStream_t stream) {
  const float* img   = (const float*)d_in[0];
  const float* cloud = (const float*)d_in[1];
  const float* c1w   = (const float*)d_in[2];
  const float* c1b   = (const float*)d_in[3];
  const float* c2w   = (const float*)d_in[4];
  const float* c2b   = (const float*)d_in[5];
  const float* ps1w  = (const float*)d_in[6];
  const float* ps1b  = (const float*)d_in[7];
  const float* ps2w  = (const float*)d_in[8];
  const float* ps2b  = (const float*)d_in[9];
  const float* p1w   = (const float*)d_in[10];
  const float* p1b   = (const float*)d_in[11];
  const float* p2w   = (const float*)d_in[12];
  const float* p2b   = (const float*)d_in[13];
  const float* fw    = (const float*)d_in[14];
  const float* fb    = (const float*)d_in[15];
  float* out = (float*)d_out;

  char* ws = (char*)d_ws;
  float4* pts4 = (float4*)(ws + 0);           // 256 KB
  float*  cf   = (float*)(ws + 262144);       // 8 MB
  float*  imfT = (float*)(ws + 8650752);      // 2 MB
  int*    nidx = (int*)  (ws + 10747904);     // 1 MB
  float*  nwgt = (float*)(ws + 11796480);     // 1 MB
  float*  sfmx = (float*)(ws + 12845056);     // 8 MB
  float*  sfpmx= (float*)(ws + 21233664);     // 8 MB
  float*  fwp  = (float*)(ws + 29622272);     // 56 KB   (total ~28.3 MB)

  prep_kernel<<<N, 128, 0, stream>>>(img, cloud, p1w, p1b, p2w, p2b, pts4, cf, imfT);
  padw_kernel<<<56, 256, 0, stream>>>(fw, fwp);
  knn_kernel<<<N / 4, 256, 0, stream>>>(pts4, nidx, nwgt);
  sf_kernel<<<N, 256, 0, stream>>>(imfT, nidx, nwgt, c1w, c1b, c2w, c2b, sfmx);
  sfp_kernel<<<N, 256, 0, stream>>>(cf, nidx, nwgt, ps1w, ps1b, ps2w, ps2b, sfpmx);
  final_kernel<<<N / 64, 256, 0, stream>>>(sfpmx, imfT, sfmx, cf, fwp, fb, out);
}

// Round 2
// 822.999 us; speedup vs baseline: 2.1187x; 2.1187x over previous
//
#include <hip/hip_runtime.h>
#include <math.h>

#define N 16384
#define KNN 16

typedef __attribute__((ext_vector_type(8))) short bf16x8;
typedef __attribute__((ext_vector_type(4))) float f32x4;

__device__ __forceinline__ float lrelu(float a) { return a > 0.f ? a : 0.01f * a; }

__device__ __forceinline__ unsigned short f2bf(float f) {
  unsigned u = __float_as_uint(f);
  u += 0x7FFF + ((u >> 16) & 1);
  return (unsigned short)(u >> 16);
}

// ---------------------------------------------------------------------------
// prep: pts4 = (x,y,z,|p|^2), cf = pconv2(lrelu(pconv1(pts))), imfT
// ---------------------------------------------------------------------------
__global__ __launch_bounds__(128) void prep_kernel(
    const float* __restrict__ img, const float* __restrict__ cloud,
    const float* __restrict__ p1w, const float* __restrict__ p1b,
    const float* __restrict__ p2w, const float* __restrict__ p2b,
    float4* __restrict__ pts4, float* __restrict__ cf, float* __restrict__ imfT) {
  int i = blockIdx.x, t = threadIdx.x;
  __shared__ float h[64];
  __shared__ float p[3];
  if (t < 3) p[t] = cloud[i * 3 + t];
  __syncthreads();
  float x = p[0], y = p[1], z = p[2];
  if (t == 0) {
    float sq = x * x + y * y + z * z;
    pts4[i] = make_float4(x, y, z, sq);
  }
  if (t < 64) {
    float a = p1b[t] + x * p1w[t * 3] + y * p1w[t * 3 + 1] + z * p1w[t * 3 + 2];
    h[t] = lrelu(a);
  }
  if (t < 32) imfT[i * 32 + t] = img[t * N + i];
  __syncthreads();
  float acc = p2b[t];
  const float* wr = p2w + t * 64;
  for (int k = 0; k < 64; ++k) acc += h[k] * wr[k];
  cf[i * 128 + t] = acc;
}

// ---------------------------------------------------------------------------
// pad final_w [32,416] -> [32,448]
// ---------------------------------------------------------------------------
__global__ void padw_kernel(const float* __restrict__ fw, float* __restrict__ fwp) {
  int t = blockIdx.x * 256 + threadIdx.x;
  if (t < 32 * 448) {
    int c = t / 448, j = t % 448;
    fwp[t] = (j < 416) ? fw[c * 416 + j] : 0.f;
  }
}

// fp32 -> bf16 weight conversion
__global__ void cvt_kernel(const float* __restrict__ s, unsigned short* __restrict__ d, int n) {
  int t = blockIdx.x * 256 + threadIdx.x;
  if (t < n) d[t] = f2bf(s[t]);
}

// ---------------------------------------------------------------------------
// KNN: one wave per query, wave-held top-16 via ballot/rare-insert.
// ---------------------------------------------------------------------------
#define TILE 2048
__global__ __launch_bounds__(256) void knn_kernel(
    const float4* __restrict__ pts4, int* __restrict__ nidx, float* __restrict__ nwgt) {
  __shared__ alignas(16) float4 tile[TILE];
  int t = threadIdx.x;
  int wv = t >> 6, lane = t & 63;
  int wid = blockIdx.x * 4 + wv;
  float4 q = pts4[wid];
  unsigned long long mykey = ~0ULL;
  unsigned long long curmax = ~0ULL;

  for (int base = 0; base < N; base += TILE) {
    __syncthreads();
    for (int e = t; e < TILE; e += 256) tile[e] = pts4[base + e];
    __syncthreads();
    for (int s = 0; s < TILE; s += 64) {
      int j = base + s + lane;
      float4 c = tile[s + lane];
      float d2 = q.w + c.w - 2.f * (q.x * c.x + q.y * c.y + q.z * c.z);
      d2 = fmaxf(d2, 0.f);
      unsigned long long key =
          ((unsigned long long)__float_as_uint(d2) << 32) | (unsigned)j;
      unsigned long long mask = __ballot(key < curmax);
      while (mask) {
        int src = __builtin_ctzll(mask);
        mask &= mask - 1;
        unsigned long long kk = __shfl(key, src);
        if (kk < curmax) {
          unsigned long long hm = __ballot(lane < KNN && mykey == curmax);
          int holder = __builtin_ctzll(hm);
          if (lane == holder) mykey = kk;
          unsigned long long m = (lane < KNN) ? mykey : 0ULL;
          #pragma unroll
          for (int off = 1; off < 64; off <<= 1) {
            unsigned long long o = __shfl_xor(m, off);
            m = (o > m) ? o : m;
          }
          curmax = m;
        }
      }
    }
  }
  int id = (lane < KNN) ? (int)(unsigned)(mykey & 0xffffffffULL) : 0;
  float4 c = pts4[id];
  float dx = q.x - c.x, dy = q.y - c.y, dz = q.z - c.z;
  float dd = dx * dx + dy * dy + dz * dz;
  float dist = sqrtf(fmaxf(dd, 1e-12f));
  float md = (lane < KNN) ? dist : INFINITY;
  #pragma unroll
  for (int off = 1; off < KNN; off <<= 1) md = fminf(md, __shfl_xor(md, off));
  float e = expf(md - dist);
  float se = (lane < KNN) ? e : 0.f;
  #pragma unroll
  for (int off = 1; off < KNN; off <<= 1) se += __shfl_xor(se, off);
  if (lane < KNN) {
    nidx[wid * KNN + lane] = id;
    nwgt[wid * KNN + lane] = e / se;
  }
}

// ---------------------------------------------------------------------------
// sfp (MFMA): 4 points/block, 4 waves. nb[64x128]bf16 -> W1[256x128] -> lrelu
// -> s1[64x256]bf16 -> W2[128x256] -> weighted max. A-frag: A[m=lane&15][k=quad*8+j],
// C/D: row=quad*4+reg, col=lane&15.
// ---------------------------------------------------------------------------
#define NB_LD 136   // 128+8 bf16: rows 272B (16B-aligned, 2-way banks = free)
#define S1_LD 264   // 256+8
__global__ __launch_bounds__(256) void sfp_kernel(
    const float* __restrict__ cf, const int* __restrict__ nidx,
    const float* __restrict__ nwgt, const unsigned short* __restrict__ w1h,
    const float* __restrict__ b1, const unsigned short* __restrict__ w2h,
    const float* __restrict__ b2, float* __restrict__ sfpmax) {
  __shared__ unsigned short nb[64 * NB_LD];
  __shared__ unsigned short s1[64 * S1_LD];
  __shared__ int ids[64];
  __shared__ float wg[64];
  int t = threadIdx.x;
  int w = t >> 6, lane = t & 63;
  int col = lane & 15, quad = lane >> 4;
  int pbase = blockIdx.x * 4;

  if (t < 64) {
    ids[t] = nidx[pbase * 16 + t];
    wg[t] = nwgt[pbase * 16 + t];
  }
  __syncthreads();
  // gather cf rows -> bf16 LDS
  for (int e = t; e < 2048; e += 256) {
    int row = e >> 5, c4 = (e & 31) << 2;
    float4 v = *(const float4*)(cf + (size_t)ids[row] * 128 + c4);
    unsigned int lo = (unsigned)f2bf(v.x) | ((unsigned)f2bf(v.y) << 16);
    unsigned int hi = (unsigned)f2bf(v.z) | ((unsigned)f2bf(v.w) << 16);
    *(uint2*)&nb[row * NB_LD + c4] = make_uint2(lo, hi);
  }
  __syncthreads();

  // layer 1: out channels [w*64, w*64+64), K=128
  f32x4 acc1[4][4];  // [tt][p]
  #pragma unroll
  for (int tt = 0; tt < 4; ++tt)
    #pragma unroll
    for (int p = 0; p < 4; ++p) acc1[tt][p] = (f32x4){0.f, 0.f, 0.f, 0.f};
  for (int k0 = 0; k0 < 128; k0 += 32) {
    bf16x8 a[4];
    #pragma unroll
    for (int p = 0; p < 4; ++p)
      a[p] = *(const bf16x8*)&nb[(p * 16 + col) * NB_LD + k0 + quad * 8];
    #pragma unroll
    for (int tt = 0; tt < 4; ++tt) {
      int n = w * 64 + tt * 16 + col;
      bf16x8 b = *(const bf16x8*)&w1h[n * 128 + k0 + quad * 8];
      #pragma unroll
      for (int p = 0; p < 4; ++p)
        acc1[tt][p] = __builtin_amdgcn_mfma_f32_16x16x32_bf16(a[p], b, acc1[tt][p], 0, 0, 0);
    }
  }
  #pragma unroll
  for (int tt = 0; tt < 4; ++tt) {
    int n = w * 64 + tt * 16 + col;
    float bb = b1[n];
    #pragma unroll
    for (int p = 0; p < 4; ++p)
      #pragma unroll
      for (int r = 0; r < 4; ++r)
        s1[(p * 16 + quad * 4 + r) * S1_LD + n] = f2bf(lrelu(acc1[tt][p][r] + bb));
  }
  __syncthreads();

  // layer 2: out channels [w*32, w*32+32), K=256
  f32x4 acc2[2][4];
  #pragma unroll
  for (int tt = 0; tt < 2; ++tt)
    #pragma unroll
    for (int p = 0; p < 4; ++p) acc2[tt][p] = (f32x4){0.f, 0.f, 0.f, 0.f};
  for (int k0 = 0; k0 < 256; k0 += 32) {
    bf16x8 a[4];
    #pragma unroll
    for (int p = 0; p < 4; ++p)
      a[p] = *(const bf16x8*)&s1[(p * 16 + col) * S1_LD + k0 + quad * 8];
    #pragma unroll
    for (int tt = 0; tt < 2; ++tt) {
      int n = w * 32 + tt * 16 + col;
      bf16x8 b = *(const bf16x8*)&w2h[n * 256 + k0 + quad * 8];
      #pragma unroll
      for (int p = 0; p < 4; ++p)
        acc2[tt][p] = __builtin_amdgcn_mfma_f32_16x16x32_bf16(a[p], b, acc2[tt][p], 0, 0, 0);
    }
  }
  #pragma unroll
  for (int tt = 0; tt < 2; ++tt) {
    int n = w * 32 + tt * 16 + col;
    float bb = b2[n];
    #pragma unroll
    for (int p = 0; p < 4; ++p) {
      float mx = -INFINITY;
      #pragma unroll
      for (int r = 0; r < 4; ++r)
        mx = fmaxf(mx, (acc2[tt][p][r] + bb) * wg[p * 16 + quad * 4 + r]);
      mx = fmaxf(mx, __shfl_xor(mx, 16));
      mx = fmaxf(mx, __shfl_xor(mx, 32));
      if (lane < 16) sfpmax[(size_t)(pbase + p) * 128 + w * 32 + tt * 16 + lane] = mx;
    }
  }
}

// ---------------------------------------------------------------------------
// sf (MFMA): same structure, 32 -> 64 -> 128
// ---------------------------------------------------------------------------
#define NI_LD 40   // 32+8
#define H1_LD 72   // 64+8
__global__ __launch_bounds__(256) void sf_kernel(
    const float* __restrict__ imfT, const int* __restrict__ nidx,
    const float* __restrict__ nwgt, const unsigned short* __restrict__ c1h,
    const float* __restrict__ c1b, const unsigned short* __restrict__ c2h,
    const float* __restrict__ c2b, float* __restrict__ sfmax) {
  __shared__ unsigned short nbi[64 * NI_LD];
  __shared__ unsigned short h1[64 * H1_LD];
  __shared__ int ids[64];
  __shared__ float wg[64];
  int t = threadIdx.x;
  int w = t >> 6, lane = t & 63;
  int col = lane & 15, quad = lane >> 4;
  int pbase = blockIdx.x * 4;

  if (t < 64) {
    ids[t] = nidx[pbase * 16 + t];
    wg[t] = nwgt[pbase * 16 + t];
  }
  __syncthreads();
  for (int e = t; e < 512; e += 256) {
    int row = e >> 3, c4 = (e & 7) << 2;
    float4 v = *(const float4*)(imfT + (size_t)ids[row] * 32 + c4);
    unsigned int lo = (unsigned)f2bf(v.x) | ((unsigned)f2bf(v.y) << 16);
    unsigned int hi = (unsigned)f2bf(v.z) | ((unsigned)f2bf(v.w) << 16);
    *(uint2*)&nbi[row * NI_LD + c4] = make_uint2(lo, hi);
  }
  __syncthreads();

  // layer 1: wave w -> channels [w*16, w*16+16), K=32 (single step)
  f32x4 accA[4];
  #pragma unroll
  for (int p = 0; p < 4; ++p) accA[p] = (f32x4){0.f, 0.f, 0.f, 0.f};
  {
    int n = w * 16 + col;
    bf16x8 b = *(const bf16x8*)&c1h[n * 32 + quad * 8];
    #pragma unroll
    for (int p = 0; p < 4; ++p) {
      bf16x8 a = *(const bf16x8*)&nbi[(p * 16 + col) * NI_LD + quad * 8];
      accA[p] = __builtin_amdgcn_mfma_f32_16x16x32_bf16(a, b, accA[p], 0, 0, 0);
    }
  }
  {
    int n = w * 16 + col;
    float bb = c1b[n];
    #pragma unroll
    for (int p = 0; p < 4; ++p)
      #pragma unroll
      for (int r = 0; r < 4; ++r)
        h1[(p * 16 + quad * 4 + r) * H1_LD + n] = f2bf(lrelu(accA[p][r] + bb));
  }
  __syncthreads();

  // layer 2: channels [w*32, w*32+32), K=64
  f32x4 acc2[2][4];
  #pragma unroll
  for (int tt = 0; tt < 2; ++tt)
    #pragma unroll
    for (int p = 0; p < 4; ++p) acc2[tt][p] = (f32x4){0.f, 0.f, 0.f, 0.f};
  for (int k0 = 0; k0 < 64; k0 += 32) {
    bf16x8 a[4];
    #pragma unroll
    for (int p = 0; p < 4; ++p)
      a[p] = *(const bf16x8*)&h1[(p * 16 + col) * H1_LD + k0 + quad * 8];
    #pragma unroll
    for (int tt = 0; tt < 2; ++tt) {
      int n = w * 32 + tt * 16 + col;
      bf16x8 b = *(const bf16x8*)&c2h[n * 64 + k0 + quad * 8];
      #pragma unroll
      for (int p = 0; p < 4; ++p)
        acc2[tt][p] = __builtin_amdgcn_mfma_f32_16x16x32_bf16(a[p], b, acc2[tt][p], 0, 0, 0);
    }
  }
  #pragma unroll
  for (int tt = 0; tt < 2; ++tt) {
    int n = w * 32 + tt * 16 + col;
    float bb = c2b[n];
    #pragma unroll
    for (int p = 0; p < 4; ++p) {
      float mx = -INFINITY;
      #pragma unroll
      for (int r = 0; r < 4; ++r)
        mx = fmaxf(mx, (acc2[tt][p][r] + bb) * wg[p * 16 + quad * 4 + r]);
      mx = fmaxf(mx, __shfl_xor(mx, 16));
      mx = fmaxf(mx, __shfl_xor(mx, 32));
      if (lane < 16) sfmax[(size_t)(pbase + p) * 128 + w * 32 + tt * 16 + lane] = mx;
    }
  }
}

// ---------------------------------------------------------------------------
// final: out[c][i] = fb[c] + sum_j lrelu(concat[i][j]) * fw[c][j]
// ---------------------------------------------------------------------------
__global__ __launch_bounds__(256) void final_kernel(
    const float* __restrict__ sfpmax, const float* __restrict__ imfT,
    const float* __restrict__ sfmax, const float* __restrict__ cf,
    const float* __restrict__ fwp, const float* __restrict__ fb,
    float* __restrict__ out) {
  __shared__ float feat[64][65];
  int t = threadIdx.x;
  int pbase = blockIdx.x * 64;
  int p = t & 63, cg = t >> 6;
  float acc[8];
  #pragma unroll
  for (int c = 0; c < 8; ++c) acc[c] = fb[cg * 8 + c];
  for (int jt = 0; jt < 448; jt += 64) {
    __syncthreads();
    for (int e = t; e < 64 * 64; e += 256) {
      int pp = e >> 6, jj = e & 63;
      int j = jt + jj;
      int pt = pbase + pp;
      float v;
      if (j < 128)      v = sfpmax[pt * 128 + j];
      else if (j < 160) v = imfT[pt * 32 + j - 128];
      else if (j < 288) v = sfmax[pt * 128 + j - 160];
      else if (j < 416) v = cf[pt * 128 + j - 288];
      else              v = 0.f;
      feat[pp][jj] = lrelu(v);
    }
    __syncthreads();
    for (int jj = 0; jj < 64; ++jj) {
      float f = feat[p][jj];
      #pragma unroll
      for (int c = 0; c < 8; ++c)
        acc[c] += f * fwp[(cg * 8 + c) * 448 + jt + jj];
    }
  }
  #pragma unroll
  for (int c = 0; c < 8; ++c) out[(cg * 8 + c) * N + pbase + p] = acc[c];
}

// ---------------------------------------------------------------------------
extern "C" void kernel_launch(void* const* d_in, const int* in_sizes, int n_in,
                              void* d_out, int out_size, void* d_ws, size_t ws_size,
                              hipStream_t stream) {
  const float* img   = (const float*)d_in[0];
  const float* cloud = (const float*)d_in[1];
  const float* c1w   = (const float*)d_in[2];
  const float* c1b   = (const float*)d_in[3];
  const float* c2w   = (const float*)d_in[4];
  const float* c2b   = (const float*)d_in[5];
  const float* ps1w  = (const float*)d_in[6];
  const float* ps1b  = (const float*)d_in[7];
  const float* ps2w  = (const float*)d_in[8];
  const float* ps2b  = (const float*)d_in[9];
  const float* p1w   = (const float*)d_in[10];
  const float* p1b   = (const float*)d_in[11];
  const float* p2w   = (const float*)d_in[12];
  const float* p2b   = (const float*)d_in[13];
  const float* fw    = (const float*)d_in[14];
  const float* fb    = (const float*)d_in[15];
  float* out = (float*)d_out;

  char* ws = (char*)d_ws;
  float4* pts4 = (float4*)(ws + 0);            // 256 KB
  float*  cf   = (float*)(ws + 262144);        // 8 MB
  float*  imfT = (float*)(ws + 8650752);       // 2 MB
  int*    nidx = (int*)  (ws + 10747904);      // 1 MB
  float*  nwgt = (float*)(ws + 11796480);      // 1 MB
  float*  sfmx = (float*)(ws + 12845056);      // 8 MB
  float*  sfpmx= (float*)(ws + 21233664);      // 8 MB
  float*  fwp  = (float*)(ws + 29622272);      // 56 KB
  unsigned short* w1h = (unsigned short*)(ws + 29679616);  // 64 KB
  unsigned short* w2h = (unsigned short*)(ws + 29745152);  // 64 KB
  unsigned short* c1h = (unsigned short*)(ws + 29810688);  // 4 KB
  unsigned short* c2h = (unsigned short*)(ws + 29814784);  // 16 KB

  cvt_kernel<<<128, 256, 0, stream>>>(ps1w, w1h, 256 * 128);
  cvt_kernel<<<128, 256, 0, stream>>>(ps2w, w2h, 128 * 256);
  cvt_kernel<<<8, 256, 0, stream>>>(c1w, c1h, 64 * 32);
  cvt_kernel<<<32, 256, 0, stream>>>(c2w, c2h, 128 * 64);
  padw_kernel<<<56, 256, 0, stream>>>(fw, fwp);

  prep_kernel<<<N, 128, 0, stream>>>(img, cloud, p1w, p1b, p2w, p2b, pts4, cf, imfT);
  knn_kernel<<<N / 4, 256, 0, stream>>>(pts4, nidx, nwgt);
  sf_kernel<<<N / 4, 256, 0, stream>>>(imfT, nidx, nwgt, c1h, c1b, c2h, c2b, sfmx);
  sfp_kernel<<<N / 4, 256, 0, stream>>>(cf, nidx, nwgt, w1h, ps1b, w2h, ps2b, sfpmx);
  final_kernel<<<N / 64, 256, 0, stream>>>(sfpmx, imfT, sfmx, cf, fwp, fb, out);
}

// Round 3
// 584.012 us; speedup vs baseline: 2.9858x; 1.4092x over previous
//
#include <hip/hip_runtime.h>
#include <math.h>

#define N 16384
#define KNN 16

typedef __attribute__((ext_vector_type(8))) short bf16x8;
typedef __attribute__((ext_vector_type(4))) float f32x4;

__device__ __forceinline__ float lrelu(float a) { return a > 0.f ? a : 0.01f * a; }

__device__ __forceinline__ unsigned short f2bf(float f) {
  unsigned u = __float_as_uint(f);
  u += 0x7FFF + ((u >> 16) & 1);
  return (unsigned short)(u >> 16);
}

// ---------------------------------------------------------------------------
// prep: pts4 = (x,y,z,|p|^2), cf = pconv2(lrelu(pconv1(pts))), imfT
// ---------------------------------------------------------------------------
__global__ __launch_bounds__(128) void prep_kernel(
    const float* __restrict__ img, const float* __restrict__ cloud,
    const float* __restrict__ p1w, const float* __restrict__ p1b,
    const float* __restrict__ p2w, const float* __restrict__ p2b,
    float4* __restrict__ pts4, float* __restrict__ cf, float* __restrict__ imfT) {
  int i = blockIdx.x, t = threadIdx.x;
  __shared__ float h[64];
  __shared__ float p[3];
  if (t < 3) p[t] = cloud[i * 3 + t];
  __syncthreads();
  float x = p[0], y = p[1], z = p[2];
  if (t == 0) {
    float sq = x * x + y * y + z * z;
    pts4[i] = make_float4(x, y, z, sq);
  }
  if (t < 64) {
    float a = p1b[t] + x * p1w[t * 3] + y * p1w[t * 3 + 1] + z * p1w[t * 3 + 2];
    h[t] = lrelu(a);
  }
  if (t < 32) imfT[i * 32 + t] = img[t * N + i];
  __syncthreads();
  float acc = p2b[t];
  const float* wr = p2w + t * 64;
  for (int k = 0; k < 64; ++k) acc += h[k] * wr[k];
  cf[i * 128 + t] = acc;
}

// ---------------------------------------------------------------------------
// pad final_w [32,416] -> [32,448]
// ---------------------------------------------------------------------------
__global__ void padw_kernel(const float* __restrict__ fw, float* __restrict__ fwp) {
  int t = blockIdx.x * 256 + threadIdx.x;
  if (t < 32 * 448) {
    int c = t / 448, j = t % 448;
    fwp[t] = (j < 416) ? fw[c * 416 + j] : 0.f;
  }
}

// fp32 -> bf16 weight conversion
__global__ void cvt_kernel(const float* __restrict__ s, unsigned short* __restrict__ d, int n) {
  int t = blockIdx.x * 256 + threadIdx.x;
  if (t < n) d[t] = f2bf(s[t]);
}

// ---------------------------------------------------------------------------
// KNN v2: buffered lazy-threshold exact top-16.
// Per candidate: d2 + compare only. Survivors -> per-wave LDS buffer via
// ballot prefix. Buffer >64 -> bitonic sort64 compaction to top-16, tighten
// tau. tau >= true 16th distance always => exact superset kept.
// ---------------------------------------------------------------------------
__device__ __forceinline__ unsigned long long bsort64(unsigned long long v, int lane) {
  #pragma unroll
  for (int k = 2; k <= 64; k <<= 1) {
    #pragma unroll
    for (int j = k >> 1; j >= 1; j >>= 1) {
      unsigned long long p = __shfl_xor(v, j);
      bool keepmin = (((lane & j) == 0) == ((lane & k) == 0));
      unsigned long long mn = v < p ? v : p;
      unsigned long long mx = v < p ? p : v;
      v = keepmin ? mn : mx;
    }
  }
  return v;
}

__device__ __forceinline__ unsigned long long bclean64(unsigned long long v, int lane) {
  #pragma unroll
  for (int j = 32; j >= 1; j >>= 1) {
    unsigned long long p = __shfl_xor(v, j);
    unsigned long long mn = v < p ? v : p;
    unsigned long long mx = v < p ? p : v;
    v = ((lane & j) == 0) ? mn : mx;
  }
  return v;
}

// sort buffer (cnt <= 128), keep exact top-16, update tau. Returns sorted keys.
__device__ __forceinline__ unsigned long long compact_topk(
    unsigned long long* buf, int& cnt, int lane, float& tau) {
  unsigned long long v = (lane < cnt) ? buf[lane] : ~0ULL;
  v = bsort64(v, lane);
  for (int base = 64; base < cnt; base += 64) {
    unsigned long long t = (base + lane < cnt) ? buf[base + lane] : ~0ULL;
    t = bsort64(t, lane);
    t = __shfl_xor(t, 63);  // reverse -> descending
    v = (t < v) ? t : v;    // lower half of 128-merge (bitonic)
    v = bclean64(v, lane);
  }
  if (lane < 16) buf[lane] = v;
  cnt = 16;
  unsigned long long k15 = __shfl(v, 15);
  tau = __uint_as_float((unsigned)(k15 >> 32));
  return v;
}

#define TILE 2048
__global__ __launch_bounds__(256) void knn_kernel(
    const float4* __restrict__ pts4, int* __restrict__ nidx, float* __restrict__ nwgt) {
  __shared__ alignas(16) float4 tile[TILE];                 // 32 KB
  __shared__ unsigned long long sbuf[4][128];               // 4 KB
  int t = threadIdx.x;
  int wv = t >> 6, lane = t & 63;
  int wid = blockIdx.x * 4 + wv;
  unsigned long long* buf = sbuf[wv];

  float4 q = pts4[wid];
  float q2x = -2.f * q.x, q2y = -2.f * q.y, q2z = -2.f * q.z;
  float tau = INFINITY;
  int cnt = 0;

  for (int base = 0; base < N; base += TILE) {
    __syncthreads();
    for (int e = t; e < TILE; e += 256) tile[e] = pts4[base + e];
    __syncthreads();
    for (int s = 0; s < TILE; s += 64) {
      float4 c = tile[s + lane];
      float d2 = fmaf(q2x, c.x, fmaf(q2y, c.y, fmaf(q2z, c.z, q.w + c.w)));
      d2 = fmaxf(d2, 0.f);
      bool pass = (d2 <= tau);
      unsigned long long mask = __ballot(pass);
      if (mask) {
        if (pass) {
          unsigned long long key =
              ((unsigned long long)__float_as_uint(d2) << 32) |
              (unsigned)(base + s + lane);
          buf[cnt + __popcll(mask & ((1ULL << lane) - 1))] = key;
        }
        cnt += __popcll(mask);
        if (cnt > 64) compact_topk(buf, cnt, lane, tau);
      }
    }
  }
  unsigned long long v = compact_topk(buf, cnt, lane, tau);

  // epilogue: lanes 0-15 hold top-16 (ascending by (d2, idx))
  int id = (lane < KNN) ? (int)(unsigned)(v & 0xffffffffULL) : 0;
  float4 c = pts4[id];
  float dx = q.x - c.x, dy = q.y - c.y, dz = q.z - c.z;
  float dd = dx * dx + dy * dy + dz * dz;
  float dist = sqrtf(fmaxf(dd, 1e-12f));
  float md = (lane < KNN) ? dist : INFINITY;
  #pragma unroll
  for (int off = 1; off < KNN; off <<= 1) md = fminf(md, __shfl_xor(md, off));
  float e = expf(md - dist);
  float se = (lane < KNN) ? e : 0.f;
  #pragma unroll
  for (int off = 1; off < KNN; off <<= 1) se += __shfl_xor(se, off);
  if (lane < KNN) {
    nidx[wid * KNN + lane] = id;
    nwgt[wid * KNN + lane] = e / se;
  }
}

// ---------------------------------------------------------------------------
// sfp (MFMA): 4 points/block, 4 waves. nb[64x128]bf16 -> W1[256x128] -> lrelu
// -> s1[64x256]bf16 -> W2[128x256] -> weighted max.
// ---------------------------------------------------------------------------
#define NB_LD 136
#define S1_LD 264
__global__ __launch_bounds__(256) void sfp_kernel(
    const float* __restrict__ cf, const int* __restrict__ nidx,
    const float* __restrict__ nwgt, const unsigned short* __restrict__ w1h,
    const float* __restrict__ b1, const unsigned short* __restrict__ w2h,
    const float* __restrict__ b2, float* __restrict__ sfpmax) {
  __shared__ unsigned short nb[64 * NB_LD];
  __shared__ unsigned short s1[64 * S1_LD];
  __shared__ int ids[64];
  __shared__ float wg[64];
  int t = threadIdx.x;
  int w = t >> 6, lane = t & 63;
  int col = lane & 15, quad = lane >> 4;
  int pbase = blockIdx.x * 4;

  if (t < 64) {
    ids[t] = nidx[pbase * 16 + t];
    wg[t] = nwgt[pbase * 16 + t];
  }
  __syncthreads();
  for (int e = t; e < 2048; e += 256) {
    int row = e >> 5, c4 = (e & 31) << 2;
    float4 v = *(const float4*)(cf + (size_t)ids[row] * 128 + c4);
    unsigned int lo = (unsigned)f2bf(v.x) | ((unsigned)f2bf(v.y) << 16);
    unsigned int hi = (unsigned)f2bf(v.z) | ((unsigned)f2bf(v.w) << 16);
    *(uint2*)&nb[row * NB_LD + c4] = make_uint2(lo, hi);
  }
  __syncthreads();

  f32x4 acc1[4][4];
  #pragma unroll
  for (int tt = 0; tt < 4; ++tt)
    #pragma unroll
    for (int p = 0; p < 4; ++p) acc1[tt][p] = (f32x4){0.f, 0.f, 0.f, 0.f};
  for (int k0 = 0; k0 < 128; k0 += 32) {
    bf16x8 a[4];
    #pragma unroll
    for (int p = 0; p < 4; ++p)
      a[p] = *(const bf16x8*)&nb[(p * 16 + col) * NB_LD + k0 + quad * 8];
    #pragma unroll
    for (int tt = 0; tt < 4; ++tt) {
      int n = w * 64 + tt * 16 + col;
      bf16x8 b = *(const bf16x8*)&w1h[n * 128 + k0 + quad * 8];
      #pragma unroll
      for (int p = 0; p < 4; ++p)
        acc1[tt][p] = __builtin_amdgcn_mfma_f32_16x16x32_bf16(a[p], b, acc1[tt][p], 0, 0, 0);
    }
  }
  #pragma unroll
  for (int tt = 0; tt < 4; ++tt) {
    int n = w * 64 + tt * 16 + col;
    float bb = b1[n];
    #pragma unroll
    for (int p = 0; p < 4; ++p)
      #pragma unroll
      for (int r = 0; r < 4; ++r)
        s1[(p * 16 + quad * 4 + r) * S1_LD + n] = f2bf(lrelu(acc1[tt][p][r] + bb));
  }
  __syncthreads();

  f32x4 acc2[2][4];
  #pragma unroll
  for (int tt = 0; tt < 2; ++tt)
    #pragma unroll
    for (int p = 0; p < 4; ++p) acc2[tt][p] = (f32x4){0.f, 0.f, 0.f, 0.f};
  for (int k0 = 0; k0 < 256; k0 += 32) {
    bf16x8 a[4];
    #pragma unroll
    for (int p = 0; p < 4; ++p)
      a[p] = *(const bf16x8*)&s1[(p * 16 + col) * S1_LD + k0 + quad * 8];
    #pragma unroll
    for (int tt = 0; tt < 2; ++tt) {
      int n = w * 32 + tt * 16 + col;
      bf16x8 b = *(const bf16x8*)&w2h[n * 256 + k0 + quad * 8];
      #pragma unroll
      for (int p = 0; p < 4; ++p)
        acc2[tt][p] = __builtin_amdgcn_mfma_f32_16x16x32_bf16(a[p], b, acc2[tt][p], 0, 0, 0);
    }
  }
  #pragma unroll
  for (int tt = 0; tt < 2; ++tt) {
    int n = w * 32 + tt * 16 + col;
    float bb = b2[n];
    #pragma unroll
    for (int p = 0; p < 4; ++p) {
      float mx = -INFINITY;
      #pragma unroll
      for (int r = 0; r < 4; ++r)
        mx = fmaxf(mx, (acc2[tt][p][r] + bb) * wg[p * 16 + quad * 4 + r]);
      mx = fmaxf(mx, __shfl_xor(mx, 16));
      mx = fmaxf(mx, __shfl_xor(mx, 32));
      if (lane < 16) sfpmax[(size_t)(pbase + p) * 128 + w * 32 + tt * 16 + lane] = mx;
    }
  }
}

// ---------------------------------------------------------------------------
// sf (MFMA): same structure, 32 -> 64 -> 128
// ---------------------------------------------------------------------------
#define NI_LD 40
#define H1_LD 72
__global__ __launch_bounds__(256) void sf_kernel(
    const float* __restrict__ imfT, const int* __restrict__ nidx,
    const float* __restrict__ nwgt, const unsigned short* __restrict__ c1h,
    const float* __restrict__ c1b, const unsigned short* __restrict__ c2h,
    const float* __restrict__ c2b, float* __restrict__ sfmax) {
  __shared__ unsigned short nbi[64 * NI_LD];
  __shared__ unsigned short h1[64 * H1_LD];
  __shared__ int ids[64];
  __shared__ float wg[64];
  int t = threadIdx.x;
  int w = t >> 6, lane = t & 63;
  int col = lane & 15, quad = lane >> 4;
  int pbase = blockIdx.x * 4;

  if (t < 64) {
    ids[t] = nidx[pbase * 16 + t];
    wg[t] = nwgt[pbase * 16 + t];
  }
  __syncthreads();
  for (int e = t; e < 512; e += 256) {
    int row = e >> 3, c4 = (e & 7) << 2;
    float4 v = *(const float4*)(imfT + (size_t)ids[row] * 32 + c4);
    unsigned int lo = (unsigned)f2bf(v.x) | ((unsigned)f2bf(v.y) << 16);
    unsigned int hi = (unsigned)f2bf(v.z) | ((unsigned)f2bf(v.w) << 16);
    *(uint2*)&nbi[row * NI_LD + c4] = make_uint2(lo, hi);
  }
  __syncthreads();

  f32x4 accA[4];
  #pragma unroll
  for (int p = 0; p < 4; ++p) accA[p] = (f32x4){0.f, 0.f, 0.f, 0.f};
  {
    int n = w * 16 + col;
    bf16x8 b = *(const bf16x8*)&c1h[n * 32 + quad * 8];
    #pragma unroll
    for (int p = 0; p < 4; ++p) {
      bf16x8 a = *(const bf16x8*)&nbi[(p * 16 + col) * NI_LD + quad * 8];
      accA[p] = __builtin_amdgcn_mfma_f32_16x16x32_bf16(a, b, accA[p], 0, 0, 0);
    }
  }
  {
    int n = w * 16 + col;
    float bb = c1b[n];
    #pragma unroll
    for (int p = 0; p < 4; ++p)
      #pragma unroll
      for (int r = 0; r < 4; ++r)
        h1[(p * 16 + quad * 4 + r) * H1_LD + n] = f2bf(lrelu(accA[p][r] + bb));
  }
  __syncthreads();

  f32x4 acc2[2][4];
  #pragma unroll
  for (int tt = 0; tt < 2; ++tt)
    #pragma unroll
    for (int p = 0; p < 4; ++p) acc2[tt][p] = (f32x4){0.f, 0.f, 0.f, 0.f};
  for (int k0 = 0; k0 < 64; k0 += 32) {
    bf16x8 a[4];
    #pragma unroll
    for (int p = 0; p < 4; ++p)
      a[p] = *(const bf16x8*)&h1[(p * 16 + col) * H1_LD + k0 + quad * 8];
    #pragma unroll
    for (int tt = 0; tt < 2; ++tt) {
      int n = w * 32 + tt * 16 + col;
      bf16x8 b = *(const bf16x8*)&c2h[n * 64 + k0 + quad * 8];
      #pragma unroll
      for (int p = 0; p < 4; ++p)
        acc2[tt][p] = __builtin_amdgcn_mfma_f32_16x16x32_bf16(a[p], b, acc2[tt][p], 0, 0, 0);
    }
  }
  #pragma unroll
  for (int tt = 0; tt < 2; ++tt) {
    int n = w * 32 + tt * 16 + col;
    float bb = c2b[n];
    #pragma unroll
    for (int p = 0; p < 4; ++p) {
      float mx = -INFINITY;
      #pragma unroll
      for (int r = 0; r < 4; ++r)
        mx = fmaxf(mx, (acc2[tt][p][r] + bb) * wg[p * 16 + quad * 4 + r]);
      mx = fmaxf(mx, __shfl_xor(mx, 16));
      mx = fmaxf(mx, __shfl_xor(mx, 32));
      if (lane < 16) sfmax[(size_t)(pbase + p) * 128 + w * 32 + tt * 16 + lane] = mx;
    }
  }
}

// ---------------------------------------------------------------------------
// final: out[c][i] = fb[c] + sum_j lrelu(concat[i][j]) * fw[c][j]
// ---------------------------------------------------------------------------
__global__ __launch_bounds__(256) void final_kernel(
    const float* __restrict__ sfpmax, const float* __restrict__ imfT,
    const float* __restrict__ sfmax, const float* __restrict__ cf,
    const float* __restrict__ fwp, const float* __restrict__ fb,
    float* __restrict__ out) {
  __shared__ float feat[64][65];
  int t = threadIdx.x;
  int pbase = blockIdx.x * 64;
  int p = t & 63, cg = t >> 6;
  float acc[8];
  #pragma unroll
  for (int c = 0; c < 8; ++c) acc[c] = fb[cg * 8 + c];
  for (int jt = 0; jt < 448; jt += 64) {
    __syncthreads();
    for (int e = t; e < 64 * 64; e += 256) {
      int pp = e >> 6, jj = e & 63;
      int j = jt + jj;
      int pt = pbase + pp;
      float v;
      if (j < 128)      v = sfpmax[pt * 128 + j];
      else if (j < 160) v = imfT[pt * 32 + j - 128];
      else if (j < 288) v = sfmax[pt * 128 + j - 160];
      else if (j < 416) v = cf[pt * 128 + j - 288];
      else              v = 0.f;
      feat[pp][jj] = lrelu(v);
    }
    __syncthreads();
    for (int jj = 0; jj < 64; ++jj) {
      float f = feat[p][jj];
      #pragma unroll
      for (int c = 0; c < 8; ++c)
        acc[c] += f * fwp[(cg * 8 + c) * 448 + jt + jj];
    }
  }
  #pragma unroll
  for (int c = 0; c < 8; ++c) out[(cg * 8 + c) * N + pbase + p] = acc[c];
}

// ---------------------------------------------------------------------------
extern "C" void kernel_launch(void* const* d_in, const int* in_sizes, int n_in,
                              void* d_out, int out_size, void* d_ws, size_t ws_size,
                              hipStream_t stream) {
  const float* img   = (const float*)d_in[0];
  const float* cloud = (const float*)d_in[1];
  const float* c1w   = (const float*)d_in[2];
  const float* c1b   = (const float*)d_in[3];
  const float* c2w   = (const float*)d_in[4];
  const float* c2b   = (const float*)d_in[5];
  const float* ps1w  = (const float*)d_in[6];
  const float* ps1b  = (const float*)d_in[7];
  const float* ps2w  = (const float*)d_in[8];
  const float* ps2b  = (const float*)d_in[9];
  const float* p1w   = (const float*)d_in[10];
  const float* p1b   = (const float*)d_in[11];
  const float* p2w   = (const float*)d_in[12];
  const float* p2b   = (const float*)d_in[13];
  const float* fw    = (const float*)d_in[14];
  const float* fb    = (const float*)d_in[15];
  float* out = (float*)d_out;

  char* ws = (char*)d_ws;
  float4* pts4 = (float4*)(ws + 0);            // 256 KB
  float*  cf   = (float*)(ws + 262144);        // 8 MB
  float*  imfT = (float*)(ws + 8650752);       // 2 MB
  int*    nidx = (int*)  (ws + 10747904);      // 1 MB
  float*  nwgt = (float*)(ws + 11796480);      // 1 MB
  float*  sfmx = (float*)(ws + 12845056);      // 8 MB
  float*  sfpmx= (float*)(ws + 21233664);      // 8 MB
  float*  fwp  = (float*)(ws + 29622272);      // 56 KB
  unsigned short* w1h = (unsigned short*)(ws + 29679616);  // 64 KB
  unsigned short* w2h = (unsigned short*)(ws + 29745152);  // 64 KB
  unsigned short* c1h = (unsigned short*)(ws + 29810688);  // 4 KB
  unsigned short* c2h = (unsigned short*)(ws + 29814784);  // 16 KB

  cvt_kernel<<<128, 256, 0, stream>>>(ps1w, w1h, 256 * 128);
  cvt_kernel<<<128, 256, 0, stream>>>(ps2w, w2h, 128 * 256);
  cvt_kernel<<<8, 256, 0, stream>>>(c1w, c1h, 64 * 32);
  cvt_kernel<<<32, 256, 0, stream>>>(c2w, c2h, 128 * 64);
  padw_kernel<<<56, 256, 0, stream>>>(fw, fwp);

  prep_kernel<<<N, 128, 0, stream>>>(img, cloud, p1w, p1b, p2w, p2b, pts4, cf, imfT);
  knn_kernel<<<N / 4, 256, 0, stream>>>(pts4, nidx, nwgt);
  sf_kernel<<<N / 4, 256, 0, stream>>>(imfT, nidx, nwgt, c1h, c1b, c2h, c2b, sfmx);
  sfp_kernel<<<N / 4, 256, 0, stream>>>(cf, nidx, nwgt, w1h, ps1b, w2h, ps2b, sfpmx);
  final_kernel<<<N / 64, 256, 0, stream>>>(sfpmx, imfT, sfmx, cf, fwp, fb, out);
}

// Round 4
// 560.633 us; speedup vs baseline: 3.1103x; 1.0417x over previous
//
#include <hip/hip_runtime.h>
#include <math.h>

#define N 16384
#define KNN 16

typedef __attribute__((ext_vector_type(8))) short bf16x8;
typedef __attribute__((ext_vector_type(4))) float f32x4;

__device__ __forceinline__ float lrelu(float a) { return a > 0.f ? a : 0.01f * a; }

__device__ __forceinline__ unsigned short f2bf(float f) {
  unsigned u = __float_as_uint(f);
  u += 0x7FFF + ((u >> 16) & 1);
  return (unsigned short)(u >> 16);
}

// ---------------------------------------------------------------------------
// prep v2: 64 points/block, 256 blocks. Weights LDS-staged (w2 transposed,
// canonical 16B/lane reads). pts4, cf (fp32), imfT all coalesced.
// ---------------------------------------------------------------------------
#define PPB 64
__global__ __launch_bounds__(256) void prep_kernel(
    const float* __restrict__ img, const float* __restrict__ cloud,
    const float* __restrict__ p1w, const float* __restrict__ p1b,
    const float* __restrict__ p2w, const float* __restrict__ p2b,
    float4* __restrict__ pts4, float* __restrict__ cf, float* __restrict__ imfT) {
  __shared__ alignas(16) float w2t[64 * 132];  // [k][ch], pad 132 (16B-aligned rows)
  __shared__ alignas(16) float hs[PPB * 68];   // [pt][k], pad 68 (16B-aligned)
  __shared__ alignas(16) float w1s[192];
  __shared__ alignas(16) float b1s[64];
  __shared__ alignas(16) float b2s[128];
  __shared__ float ptmp[PPB * 3];
  __shared__ float psx[PPB], psy[PPB], psz[PPB];
  int t = threadIdx.x;
  int pb = blockIdx.x * PPB;

  for (int e = t; e < 128 * 64; e += 256) {
    int ch = e >> 6, k = e & 63;
    w2t[k * 132 + ch] = p2w[e];
  }
  if (t < 192) w1s[t] = p1w[t];
  if (t < 64) b1s[t] = p1b[t];
  if (t < 128) b2s[t] = p2b[t];
  if (t < PPB * 3) ptmp[t] = cloud[pb * 3 + t];
  __syncthreads();
  if (t < PPB) {
    float x = ptmp[t * 3], y = ptmp[t * 3 + 1], z = ptmp[t * 3 + 2];
    psx[t] = x; psy[t] = y; psz[t] = z;
    pts4[pb + t] = make_float4(x, y, z, x * x + y * y + z * z);
  }
  // imfT transpose (global->global, both sides coalesced on read)
  for (int e = t; e < 32 * PPB; e += 256) {
    int c = e >> 6, p = e & 63;
    imfT[(size_t)(pb + p) * 32 + c] = img[(size_t)c * N + pb + p];
  }
  __syncthreads();
  // h = lrelu(p1 @ pt + b1): 64 pts x 64 ch
  for (int e = t; e < PPB * 64; e += 256) {
    int pt_ = e >> 6, ch = e & 63;
    float a = b1s[ch] + psx[pt_] * w1s[ch * 3] + psy[pt_] * w1s[ch * 3 + 1] +
              psz[pt_] * w1s[ch * 3 + 2];
    hs[pt_ * 68 + ch] = lrelu(a);
  }
  __syncthreads();
  // cf: thread -> (pt, 4 channels); k blocked by 4
  for (int e = t; e < PPB * 32; e += 256) {
    int pt_ = e >> 5, c4 = (e & 31) << 2;
    float4 acc = *(const float4*)&b2s[c4];
    const float* hrow = &hs[pt_ * 68];
    #pragma unroll
    for (int k = 0; k < 64; k += 4) {
      float4 h4 = *(const float4*)&hrow[k];
      float4 w0 = *(const float4*)&w2t[(k + 0) * 132 + c4];
      float4 w1_ = *(const float4*)&w2t[(k + 1) * 132 + c4];
      float4 w2_ = *(const float4*)&w2t[(k + 2) * 132 + c4];
      float4 w3 = *(const float4*)&w2t[(k + 3) * 132 + c4];
      acc.x = fmaf(h4.x, w0.x, fmaf(h4.y, w1_.x, fmaf(h4.z, w2_.x, fmaf(h4.w, w3.x, acc.x))));
      acc.y = fmaf(h4.x, w0.y, fmaf(h4.y, w1_.y, fmaf(h4.z, w2_.y, fmaf(h4.w, w3.y, acc.y))));
      acc.z = fmaf(h4.x, w0.z, fmaf(h4.y, w1_.z, fmaf(h4.z, w2_.z, fmaf(h4.w, w3.z, acc.z))));
      acc.w = fmaf(h4.x, w0.w, fmaf(h4.y, w1_.w, fmaf(h4.z, w2_.w, fmaf(h4.w, w3.w, acc.w))));
    }
    *(float4*)&cf[(size_t)(pb + pt_) * 128 + c4] = acc;
  }
}

// ---------------------------------------------------------------------------
// pad final_w [32,416] -> [32,448]
// ---------------------------------------------------------------------------
__global__ void padw_kernel(const float* __restrict__ fw, float* __restrict__ fwp) {
  int t = blockIdx.x * 256 + threadIdx.x;
  if (t < 32 * 448) {
    int c = t / 448, j = t % 448;
    fwp[t] = (j < 416) ? fw[c * 416 + j] : 0.f;
  }
}

// fp32 -> bf16 weight conversion
__global__ void cvt_kernel(const float* __restrict__ s, unsigned short* __restrict__ d, int n) {
  int t = blockIdx.x * 256 + threadIdx.x;
  if (t < n) d[t] = f2bf(s[t]);
}

// ---------------------------------------------------------------------------
// KNN v3: 8 queries/wave, lazy-threshold buffered exact top-16 with seed peel.
// ---------------------------------------------------------------------------
#define QPW 8
__device__ __forceinline__ unsigned long long bsort64(unsigned long long v, int lane) {
  #pragma unroll
  for (int k = 2; k <= 64; k <<= 1) {
    #pragma unroll
    for (int j = k >> 1; j >= 1; j >>= 1) {
      unsigned long long p = __shfl_xor(v, j);
      bool keepmin = (((lane & j) == 0) == ((lane & k) == 0));
      unsigned long long mn = v < p ? v : p;
      unsigned long long mx = v < p ? p : v;
      v = keepmin ? mn : mx;
    }
  }
  return v;
}

__device__ __forceinline__ unsigned long long bclean64(unsigned long long v, int lane) {
  #pragma unroll
  for (int j = 32; j >= 1; j >>= 1) {
    unsigned long long p = __shfl_xor(v, j);
    unsigned long long mn = v < p ? v : p;
    unsigned long long mx = v < p ? p : v;
    v = ((lane & j) == 0) ? mn : mx;
  }
  return v;
}

// interleaved 8-query bitonic sort64 (ILP hides shfl latency)
__device__ __forceinline__ void msort64(unsigned long long v[QPW], int lane) {
  #pragma unroll
  for (int k = 2; k <= 64; k <<= 1) {
    #pragma unroll
    for (int j = k >> 1; j >= 1; j >>= 1) {
      bool keepmin = (((lane & j) == 0) == ((lane & k) == 0));
      #pragma unroll
      for (int q = 0; q < QPW; ++q) {
        unsigned long long p = __shfl_xor(v[q], j);
        unsigned long long mn = v[q] < p ? v[q] : p;
        unsigned long long mx = v[q] < p ? p : v[q];
        v[q] = keepmin ? mn : mx;
      }
    }
  }
}

// single-query: sort buffer (cnt <= 128), keep exact top-16, tighten tau
__device__ __forceinline__ void compact_topk(
    unsigned long long* buf, int& cnt, int lane, float& tau) {
  unsigned long long v = (lane < cnt) ? buf[lane] : ~0ULL;
  v = bsort64(v, lane);
  if (cnt > 64) {
    unsigned long long t = (64 + lane < cnt) ? buf[64 + lane] : ~0ULL;
    t = bsort64(t, lane);
    t = __shfl_xor(t, 63);
    v = (t < v) ? t : v;
    v = bclean64(v, lane);
  }
  if (lane < 16) buf[lane] = v;
  cnt = 16;
  unsigned long long k15 = __shfl(v, 15);
  tau = __uint_as_float((unsigned)(k15 >> 32));
}

#define TILE 2048
__global__ __launch_bounds__(256) void knn_kernel(
    const float4* __restrict__ pts4, int* __restrict__ nidx, float* __restrict__ nwgt) {
  __shared__ alignas(16) float4 tile[TILE];                // 32 KB
  __shared__ unsigned long long sbuf[4][QPW][128];         // 32 KB
  int t = threadIdx.x;
  int wv = t >> 6, lane = t & 63;
  int qbase = blockIdx.x * (4 * QPW) + wv * QPW;
  unsigned long long(*buf)[128] = sbuf[wv];

  float q2x[QPW], q2y[QPW], q2z[QPW], qw[QPW], tau[QPW];
  int cnt[QPW];
  #pragma unroll
  for (int q = 0; q < QPW; ++q) {
    float4 qq = pts4[qbase + q];
    q2x[q] = -2.f * qq.x; q2y[q] = -2.f * qq.y; q2z[q] = -2.f * qq.z;
    qw[q] = qq.w;
  }

  // ---- seed peel: candidates 0..63, sorted 8-wide interleaved -> tight tau
  {
    float4 c = pts4[lane];
    unsigned long long v[QPW];
    #pragma unroll
    for (int q = 0; q < QPW; ++q) {
      float d2 = fmaf(q2x[q], c.x, fmaf(q2y[q], c.y, fmaf(q2z[q], c.z, qw[q] + c.w)));
      d2 = fmaxf(d2, 0.f);
      v[q] = ((unsigned long long)__float_as_uint(d2) << 32) | (unsigned)lane;
    }
    msort64(v, lane);
    #pragma unroll
    for (int q = 0; q < QPW; ++q) {
      if (lane < 16) buf[q][lane] = v[q];
      unsigned long long k15 = __shfl(v[q], 15);
      tau[q] = __uint_as_float((unsigned)(k15 >> 32));
      cnt[q] = 16;
    }
  }

  for (int base = 0; base < N; base += TILE) {
    __syncthreads();
    for (int e = t; e < TILE; e += 256) tile[e] = pts4[base + e];
    __syncthreads();
    int s0 = (base == 0) ? 64 : 0;  // skip seeded candidates
    for (int s = s0; s < TILE; s += 64) {
      float4 c = tile[s + lane];
      #pragma unroll
      for (int q = 0; q < QPW; ++q) {
        float d2 = fmaf(q2x[q], c.x, fmaf(q2y[q], c.y, fmaf(q2z[q], c.z, qw[q] + c.w)));
        d2 = fmaxf(d2, 0.f);
        bool pass = (d2 <= tau[q]);
        unsigned long long mask = __ballot(pass);
        if (mask) {
          if (pass) {
            unsigned long long key =
                ((unsigned long long)__float_as_uint(d2) << 32) |
                (unsigned)(base + s + lane);
            buf[q][cnt[q] + __popcll(mask & ((1ULL << lane) - 1))] = key;
          }
          cnt[q] += __popcll(mask);
          if (cnt[q] > 64) compact_topk(buf[q], cnt[q], lane, tau[q]);
        }
      }
    }
  }

  // final: interleaved sort (cnt <= 64 per query)
  unsigned long long v[QPW];
  #pragma unroll
  for (int q = 0; q < QPW; ++q) v[q] = (lane < cnt[q]) ? buf[q][lane] : ~0ULL;
  msort64(v, lane);

  #pragma unroll
  for (int q = 0; q < QPW; ++q) {
    int wid = qbase + q;
    int id = (lane < KNN) ? (int)(unsigned)(v[q] & 0xffffffffULL) : 0;
    float4 c = pts4[id];
    float qx = -0.5f * q2x[q], qy = -0.5f * q2y[q], qz = -0.5f * q2z[q];
    float dx = qx - c.x, dy = qy - c.y, dz = qz - c.z;
    float dd = dx * dx + dy * dy + dz * dz;
    float dist = sqrtf(fmaxf(dd, 1e-12f));
    float md = (lane < KNN) ? dist : INFINITY;
    #pragma unroll
    for (int off = 1; off < KNN; off <<= 1) md = fminf(md, __shfl_xor(md, off));
    float e = expf(md - dist);
    float se = (lane < KNN) ? e : 0.f;
    #pragma unroll
    for (int off = 1; off < KNN; off <<= 1) se += __shfl_xor(se, off);
    if (lane < KNN) {
      nidx[wid * KNN + lane] = id;
      nwgt[wid * KNN + lane] = e / se;
    }
  }
}

// ---------------------------------------------------------------------------
// sfp (MFMA): 4 points/block, 4 waves. nb[64x128]bf16 -> W1[256x128] -> lrelu
// -> s1[64x256]bf16 -> W2[128x256] -> weighted max.
// ---------------------------------------------------------------------------
#define NB_LD 136
#define S1_LD 264
__global__ __launch_bounds__(256) void sfp_kernel(
    const float* __restrict__ cf, const int* __restrict__ nidx,
    const float* __restrict__ nwgt, const unsigned short* __restrict__ w1h,
    const float* __restrict__ b1, const unsigned short* __restrict__ w2h,
    const float* __restrict__ b2, float* __restrict__ sfpmax) {
  __shared__ unsigned short nb[64 * NB_LD];
  __shared__ unsigned short s1[64 * S1_LD];
  __shared__ int ids[64];
  __shared__ float wg[64];
  int t = threadIdx.x;
  int w = t >> 6, lane = t & 63;
  int col = lane & 15, quad = lane >> 4;
  int pbase = blockIdx.x * 4;

  if (t < 64) {
    ids[t] = nidx[pbase * 16 + t];
    wg[t] = nwgt[pbase * 16 + t];
  }
  __syncthreads();
  for (int e = t; e < 2048; e += 256) {
    int row = e >> 5, c4 = (e & 31) << 2;
    float4 v = *(const float4*)(cf + (size_t)ids[row] * 128 + c4);
    unsigned int lo = (unsigned)f2bf(v.x) | ((unsigned)f2bf(v.y) << 16);
    unsigned int hi = (unsigned)f2bf(v.z) | ((unsigned)f2bf(v.w) << 16);
    *(uint2*)&nb[row * NB_LD + c4] = make_uint2(lo, hi);
  }
  __syncthreads();

  f32x4 acc1[4][4];
  #pragma unroll
  for (int tt = 0; tt < 4; ++tt)
    #pragma unroll
    for (int p = 0; p < 4; ++p) acc1[tt][p] = (f32x4){0.f, 0.f, 0.f, 0.f};
  for (int k0 = 0; k0 < 128; k0 += 32) {
    bf16x8 a[4];
    #pragma unroll
    for (int p = 0; p < 4; ++p)
      a[p] = *(const bf16x8*)&nb[(p * 16 + col) * NB_LD + k0 + quad * 8];
    #pragma unroll
    for (int tt = 0; tt < 4; ++tt) {
      int n = w * 64 + tt * 16 + col;
      bf16x8 b = *(const bf16x8*)&w1h[n * 128 + k0 + quad * 8];
      #pragma unroll
      for (int p = 0; p < 4; ++p)
        acc1[tt][p] = __builtin_amdgcn_mfma_f32_16x16x32_bf16(a[p], b, acc1[tt][p], 0, 0, 0);
    }
  }
  #pragma unroll
  for (int tt = 0; tt < 4; ++tt) {
    int n = w * 64 + tt * 16 + col;
    float bb = b1[n];
    #pragma unroll
    for (int p = 0; p < 4; ++p)
      #pragma unroll
      for (int r = 0; r < 4; ++r)
        s1[(p * 16 + quad * 4 + r) * S1_LD + n] = f2bf(lrelu(acc1[tt][p][r] + bb));
  }
  __syncthreads();

  f32x4 acc2[2][4];
  #pragma unroll
  for (int tt = 0; tt < 2; ++tt)
    #pragma unroll
    for (int p = 0; p < 4; ++p) acc2[tt][p] = (f32x4){0.f, 0.f, 0.f, 0.f};
  for (int k0 = 0; k0 < 256; k0 += 32) {
    bf16x8 a[4];
    #pragma unroll
    for (int p = 0; p < 4; ++p)
      a[p] = *(const bf16x8*)&s1[(p * 16 + col) * S1_LD + k0 + quad * 8];
    #pragma unroll
    for (int tt = 0; tt < 2; ++tt) {
      int n = w * 32 + tt * 16 + col;
      bf16x8 b = *(const bf16x8*)&w2h[n * 256 + k0 + quad * 8];
      #pragma unroll
      for (int p = 0; p < 4; ++p)
        acc2[tt][p] = __builtin_amdgcn_mfma_f32_16x16x32_bf16(a[p], b, acc2[tt][p], 0, 0, 0);
    }
  }
  #pragma unroll
  for (int tt = 0; tt < 2; ++tt) {
    int n = w * 32 + tt * 16 + col;
    float bb = b2[n];
    #pragma unroll
    for (int p = 0; p < 4; ++p) {
      float mx = -INFINITY;
      #pragma unroll
      for (int r = 0; r < 4; ++r)
        mx = fmaxf(mx, (acc2[tt][p][r] + bb) * wg[p * 16 + quad * 4 + r]);
      mx = fmaxf(mx, __shfl_xor(mx, 16));
      mx = fmaxf(mx, __shfl_xor(mx, 32));
      if (lane < 16) sfpmax[(size_t)(pbase + p) * 128 + w * 32 + tt * 16 + lane] = mx;
    }
  }
}

// ---------------------------------------------------------------------------
// sf (MFMA): same structure, 32 -> 64 -> 128
// ---------------------------------------------------------------------------
#define NI_LD 40
#define H1_LD 72
__global__ __launch_bounds__(256) void sf_kernel(
    const float* __restrict__ imfT, const int* __restrict__ nidx,
    const float* __restrict__ nwgt, const unsigned short* __restrict__ c1h,
    const float* __restrict__ c1b, const unsigned short* __restrict__ c2h,
    const float* __restrict__ c2b, float* __restrict__ sfmax) {
  __shared__ unsigned short nbi[64 * NI_LD];
  __shared__ unsigned short h1[64 * H1_LD];
  __shared__ int ids[64];
  __shared__ float wg[64];
  int t = threadIdx.x;
  int w = t >> 6, lane = t & 63;
  int col = lane & 15, quad = lane >> 4;
  int pbase = blockIdx.x * 4;

  if (t < 64) {
    ids[t] = nidx[pbase * 16 + t];
    wg[t] = nwgt[pbase * 16 + t];
  }
  __syncthreads();
  for (int e = t; e < 512; e += 256) {
    int row = e >> 3, c4 = (e & 7) << 2;
    float4 v = *(const float4*)(imfT + (size_t)ids[row] * 32 + c4);
    unsigned int lo = (unsigned)f2bf(v.x) | ((unsigned)f2bf(v.y) << 16);
    unsigned int hi = (unsigned)f2bf(v.z) | ((unsigned)f2bf(v.w) << 16);
    *(uint2*)&nbi[row * NI_LD + c4] = make_uint2(lo, hi);
  }
  __syncthreads();

  f32x4 accA[4];
  #pragma unroll
  for (int p = 0; p < 4; ++p) accA[p] = (f32x4){0.f, 0.f, 0.f, 0.f};
  {
    int n = w * 16 + col;
    bf16x8 b = *(const bf16x8*)&c1h[n * 32 + quad * 8];
    #pragma unroll
    for (int p = 0; p < 4; ++p) {
      bf16x8 a = *(const bf16x8*)&nbi[(p * 16 + col) * NI_LD + quad * 8];
      accA[p] = __builtin_amdgcn_mfma_f32_16x16x32_bf16(a, b, accA[p], 0, 0, 0);
    }
  }
  {
    int n = w * 16 + col;
    float bb = c1b[n];
    #pragma unroll
    for (int p = 0; p < 4; ++p)
      #pragma unroll
      for (int r = 0; r < 4; ++r)
        h1[(p * 16 + quad * 4 + r) * H1_LD + n] = f2bf(lrelu(accA[p][r] + bb));
  }
  __syncthreads();

  f32x4 acc2[2][4];
  #pragma unroll
  for (int tt = 0; tt < 2; ++tt)
    #pragma unroll
    for (int p = 0; p < 4; ++p) acc2[tt][p] = (f32x4){0.f, 0.f, 0.f, 0.f};
  for (int k0 = 0; k0 < 64; k0 += 32) {
    bf16x8 a[4];
    #pragma unroll
    for (int p = 0; p < 4; ++p)
      a[p] = *(const bf16x8*)&h1[(p * 16 + col) * H1_LD + k0 + quad * 8];
    #pragma unroll
    for (int tt = 0; tt < 2; ++tt) {
      int n = w * 32 + tt * 16 + col;
      bf16x8 b = *(const bf16x8*)&c2h[n * 64 + k0 + quad * 8];
      #pragma unroll
      for (int p = 0; p < 4; ++p)
        acc2[tt][p] = __builtin_amdgcn_mfma_f32_16x16x32_bf16(a[p], b, acc2[tt][p], 0, 0, 0);
    }
  }
  #pragma unroll
  for (int tt = 0; tt < 2; ++tt) {
    int n = w * 32 + tt * 16 + col;
    float bb = c2b[n];
    #pragma unroll
    for (int p = 0; p < 4; ++p) {
      float mx = -INFINITY;
      #pragma unroll
      for (int r = 0; r < 4; ++r)
        mx = fmaxf(mx, (acc2[tt][p][r] + bb) * wg[p * 16 + quad * 4 + r]);
      mx = fmaxf(mx, __shfl_xor(mx, 16));
      mx = fmaxf(mx, __shfl_xor(mx, 32));
      if (lane < 16) sfmax[(size_t)(pbase + p) * 128 + w * 32 + tt * 16 + lane] = mx;
    }
  }
}

// ---------------------------------------------------------------------------
// final: out[c][i] = fb[c] + sum_j lrelu(concat[i][j]) * fw[c][j]
// ---------------------------------------------------------------------------
__global__ __launch_bounds__(256) void final_kernel(
    const float* __restrict__ sfpmax, const float* __restrict__ imfT,
    const float* __restrict__ sfmax, const float* __restrict__ cf,
    const float* __restrict__ fwp, const float* __restrict__ fb,
    float* __restrict__ out) {
  __shared__ float feat[64][65];
  int t = threadIdx.x;
  int pbase = blockIdx.x * 64;
  int p = t & 63, cg = t >> 6;
  float acc[8];
  #pragma unroll
  for (int c = 0; c < 8; ++c) acc[c] = fb[cg * 8 + c];
  for (int jt = 0; jt < 448; jt += 64) {
    __syncthreads();
    for (int e = t; e < 64 * 64; e += 256) {
      int pp = e >> 6, jj = e & 63;
      int j = jt + jj;
      int pt = pbase + pp;
      float v;
      if (j < 128)      v = sfpmax[pt * 128 + j];
      else if (j < 160) v = imfT[pt * 32 + j - 128];
      else if (j < 288) v = sfmax[pt * 128 + j - 160];
      else if (j < 416) v = cf[pt * 128 + j - 288];
      else              v = 0.f;
      feat[pp][jj] = lrelu(v);
    }
    __syncthreads();
    for (int jj = 0; jj < 64; ++jj) {
      float f = feat[p][jj];
      #pragma unroll
      for (int c = 0; c < 8; ++c)
        acc[c] += f * fwp[(cg * 8 + c) * 448 + jt + jj];
    }
  }
  #pragma unroll
  for (int c = 0; c < 8; ++c) out[(cg * 8 + c) * N + pbase + p] = acc[c];
}

// ---------------------------------------------------------------------------
extern "C" void kernel_launch(void* const* d_in, const int* in_sizes, int n_in,
                              void* d_out, int out_size, void* d_ws, size_t ws_size,
                              hipStream_t stream) {
  const float* img   = (const float*)d_in[0];
  const float* cloud = (const float*)d_in[1];
  const float* c1w   = (const float*)d_in[2];
  const float* c1b   = (const float*)d_in[3];
  const float* c2w   = (const float*)d_in[4];
  const float* c2b   = (const float*)d_in[5];
  const float* ps1w  = (const float*)d_in[6];
  const float* ps1b  = (const float*)d_in[7];
  const float* ps2w  = (const float*)d_in[8];
  const float* ps2b  = (const float*)d_in[9];
  const float* p1w   = (const float*)d_in[10];
  const float* p1b   = (const float*)d_in[11];
  const float* p2w   = (const float*)d_in[12];
  const float* p2b   = (const float*)d_in[13];
  const float* fw    = (const float*)d_in[14];
  const float* fb    = (const float*)d_in[15];
  float* out = (float*)d_out;

  char* ws = (char*)d_ws;
  float4* pts4 = (float4*)(ws + 0);            // 256 KB
  float*  cf   = (float*)(ws + 262144);        // 8 MB
  float*  imfT = (float*)(ws + 8650752);       // 2 MB
  int*    nidx = (int*)  (ws + 10747904);      // 1 MB
  float*  nwgt = (float*)(ws + 11796480);      // 1 MB
  float*  sfmx = (float*)(ws + 12845056);      // 8 MB
  float*  sfpmx= (float*)(ws + 21233664);      // 8 MB
  float*  fwp  = (float*)(ws + 29622272);      // 56 KB
  unsigned short* w1h = (unsigned short*)(ws + 29679616);  // 64 KB
  unsigned short* w2h = (unsigned short*)(ws + 29745152);  // 64 KB
  unsigned short* c1h = (unsigned short*)(ws + 29810688);  // 4 KB
  unsigned short* c2h = (unsigned short*)(ws + 29814784);  // 16 KB

  cvt_kernel<<<128, 256, 0, stream>>>(ps1w, w1h, 256 * 128);
  cvt_kernel<<<128, 256, 0, stream>>>(ps2w, w2h, 128 * 256);
  cvt_kernel<<<8, 256, 0, stream>>>(c1w, c1h, 64 * 32);
  cvt_kernel<<<32, 256, 0, stream>>>(c2w, c2h, 128 * 64);
  padw_kernel<<<56, 256, 0, stream>>>(fw, fwp);

  prep_kernel<<<N / PPB, 256, 0, stream>>>(img, cloud, p1w, p1b, p2w, p2b, pts4, cf, imfT);
  knn_kernel<<<N / (4 * QPW), 256, 0, stream>>>(pts4, nidx, nwgt);
  sf_kernel<<<N / 4, 256, 0, stream>>>(imfT, nidx, nwgt, c1h, c1b, c2h, c2b, sfmx);
  sfp_kernel<<<N / 4, 256, 0, stream>>>(cf, nidx, nwgt, w1h, ps1b, w2h, ps2b, sfpmx);
  final_kernel<<<N / 64, 256, 0, stream>>>(sfpmx, imfT, sfmx, cf, fwp, fb, out);
}